// Round 3
// baseline (407.932 us; speedup 1.0000x reference)
//
#include <hip/hip_runtime.h>
#include <math.h>

// PathPreservingNetwork — factored-class + bf16x3 MFMA implementation (R3).
// Classes per layer input: 1,1,3,7,15,31; every path value is s*C[class].
// All six GEMMs run on matrix cores with hi/lo bf16 split (3 MFMAs per tile):
// error ~2^-17 rel, far under the 9.2e-4 threshold. Prune ties stay exact
// (keys computed once per class/sign). Layouts verified per learn_hip m89/m92:
//   A-frag: A[m=lane&15][k=(lane>>4)*8+j]   (row-major M x K, k contiguous)
//   B-frag: B[k=(lane>>4)*8+j][n=lane&15]   (staged as W^T rows, k contiguous)
//   C/D   : col=lane&15, row=(lane>>4)*4+reg

using s8v = __attribute__((ext_vector_type(8))) short;
using f4v = __attribute__((ext_vector_type(4))) float;

__device__ __forceinline__ float bf2f(short b) {
  unsigned u = ((unsigned)(unsigned short)b) << 16;
  return __builtin_bit_cast(float, u);
}
__device__ __forceinline__ short f2bf(float f) {
  unsigned u = __builtin_bit_cast(unsigned, f);
  u = (u + 0x7FFFu + ((u >> 16) & 1u)) >> 16;
  return (short)u;
}
__device__ __forceinline__ void split_store(float f, short* hi, short* lo) {
  short h = f2bf(f);
  *hi = h;
  *lo = f2bf(f - bf2f(h));
}

// Pack fp32 x (128x1024) into hi/lo bf16 arrays.
__global__ void __launch_bounds__(256)
packx_k(const float* __restrict__ x, short* __restrict__ hi,
        short* __restrict__ lo) {
  int i = (blockIdx.x * 256 + threadIdx.x) * 4;
  float4 v = *(const float4*)&x[i];
  short4 h, l;
  h.x = f2bf(v.x); l.x = f2bf(v.x - bf2f(h.x));
  h.y = f2bf(v.y); l.y = f2bf(v.y - bf2f(h.y));
  h.z = f2bf(v.z); l.z = f2bf(v.z - bf2f(h.z));
  h.w = f2bf(v.w); l.w = f2bf(v.w - bf2f(h.w));
  *(short4*)&hi[i] = h;
  *(short4*)&lo[i] = l;
}

// Transpose+split W (1024 x N fp32) -> Wt hi/lo (N x 1024 bf16).
__global__ void __launch_bounds__(256)
transW_k(const float* __restrict__ W, short* __restrict__ Th,
         short* __restrict__ Tl, int N) {
  __shared__ float tile[64][65];
  const int t = threadIdx.x;
  const int n0 = blockIdx.x * 64, k0 = blockIdx.y * 64;
  const int r = t >> 4, c4 = (t & 15) * 4;
#pragma unroll
  for (int i = 0; i < 4; ++i) {
    int rr = r + 16 * i;
    float4 v = *(const float4*)&W[(size_t)(k0 + rr) * N + n0 + c4];
    tile[rr][c4 + 0] = v.x;
    tile[rr][c4 + 1] = v.y;
    tile[rr][c4 + 2] = v.z;
    tile[rr][c4 + 3] = v.w;
  }
  __syncthreads();
#pragma unroll
  for (int i = 0; i < 4; ++i) {
    int n = r + 16 * i;
    short4 h, l;
    float f0 = tile[c4 + 0][n], f1 = tile[c4 + 1][n];
    float f2 = tile[c4 + 2][n], f3 = tile[c4 + 3][n];
    h.x = f2bf(f0); l.x = f2bf(f0 - bf2f(h.x));
    h.y = f2bf(f1); l.y = f2bf(f1 - bf2f(h.y));
    h.z = f2bf(f2); l.z = f2bf(f2 - bf2f(h.z));
    h.w = f2bf(f3); l.w = f2bf(f3 - bf2f(h.w));
    size_t o = (size_t)(n0 + n) * 1024 + k0 + c4;
    *(short4*)&Th[o] = h;
    *(short4*)&Tl[o] = l;
  }
}

// ------------------------------------------------------------- MFMA GEMM ----
// A (M x 1024) hi/lo bf16 row-major; Wt (N x 1024) hi/lo bf16 row-major.
// Block tile 64 x BN, 4 waves (2x2), wave tile 32 x (BN/2). BK=32.
// MODE 0: O[rr] = tanh(bias + acc)                          (hi/lo out)
// MODE 1: O rows b*Dn+1+2u / +2+2u = tanh(bias -/+ acc); u==0 also writes
//         the zero-class row tanh(bias).                    (hi/lo out)
// MODE 2: Of[rr] = acc (raw fp32)
template <int BN, int MODE, int D>
__global__ void __launch_bounds__(256)
mfma_gemm(const short* __restrict__ Ah, const short* __restrict__ Al,
          const short* __restrict__ Bh, const short* __restrict__ Bl,
          const float* __restrict__ bias, short* __restrict__ Oh,
          short* __restrict__ Ol, float* __restrict__ Of, int N, int Dn) {
  constexpr int NB = BN / 64;
  constexpr int WN = BN / 2;
  constexpr int NT = WN / 16;
  constexpr int BKP = 40;  // pad: bank-quad stride 5 (coprime 8) -> <=2-way
  __shared__ short As_h[64 * BKP], As_l[64 * BKP];
  __shared__ short Bs_h[BN * BKP], Bs_l[BN * BKP];
  const int t = threadIdx.x;
  const int row0 = blockIdx.y * 64;
  const int col0 = blockIdx.x * BN;
  const int sr = t >> 2, sko = (t & 3) * 8;
  const short* Ahp = Ah + (size_t)(row0 + sr) * 1024 + sko;
  const short* Alp = Al + (size_t)(row0 + sr) * 1024 + sko;
  const short* Bhp = Bh + (size_t)(col0 + sr) * 1024 + sko;
  const short* Blp = Bl + (size_t)(col0 + sr) * 1024 + sko;
  const int w = t >> 6, lane = t & 63;
  const int l16 = lane & 15, q = lane >> 4;
  const int wm0 = (w & 1) * 32, wn0 = (w >> 1) * WN;
  const int abase = (wm0 + l16) * BKP + q * 8;
  const int bbase = (wn0 + l16) * BKP + q * 8;
  f4v acc[2][NT];
#pragma unroll
  for (int i = 0; i < 2; ++i)
#pragma unroll
    for (int j = 0; j < NT; ++j) acc[i][j] = (f4v){0.f, 0.f, 0.f, 0.f};
  for (int k0 = 0; k0 < 1024; k0 += 32) {
    uint4 rah = *(const uint4*)(Ahp + k0);
    uint4 ral = *(const uint4*)(Alp + k0);
    uint4 rbh[NB], rbl[NB];
#pragma unroll
    for (int ib = 0; ib < NB; ++ib) {
      rbh[ib] = *(const uint4*)(Bhp + (size_t)ib * 65536 + k0);
      rbl[ib] = *(const uint4*)(Blp + (size_t)ib * 65536 + k0);
    }
    __syncthreads();
    *(uint4*)&As_h[sr * BKP + sko] = rah;
    *(uint4*)&As_l[sr * BKP + sko] = ral;
#pragma unroll
    for (int ib = 0; ib < NB; ++ib) {
      *(uint4*)&Bs_h[(sr + ib * 64) * BKP + sko] = rbh[ib];
      *(uint4*)&Bs_l[(sr + ib * 64) * BKP + sko] = rbl[ib];
    }
    __syncthreads();
    s8v ah[2], al[2], bh[NT], bl[NT];
#pragma unroll
    for (int mt = 0; mt < 2; ++mt) {
      ah[mt] = *(const s8v*)&As_h[abase + mt * 16 * BKP];
      al[mt] = *(const s8v*)&As_l[abase + mt * 16 * BKP];
    }
#pragma unroll
    for (int nt = 0; nt < NT; ++nt) {
      bh[nt] = *(const s8v*)&Bs_h[bbase + nt * 16 * BKP];
      bl[nt] = *(const s8v*)&Bs_l[bbase + nt * 16 * BKP];
    }
#pragma unroll
    for (int mt = 0; mt < 2; ++mt)
#pragma unroll
      for (int nt = 0; nt < NT; ++nt) {
        acc[mt][nt] = __builtin_amdgcn_mfma_f32_16x16x32_bf16(
            ah[mt], bh[nt], acc[mt][nt], 0, 0, 0);
        acc[mt][nt] = __builtin_amdgcn_mfma_f32_16x16x32_bf16(
            ah[mt], bl[nt], acc[mt][nt], 0, 0, 0);
        acc[mt][nt] = __builtin_amdgcn_mfma_f32_16x16x32_bf16(
            al[mt], bh[nt], acc[mt][nt], 0, 0, 0);
      }
  }
#pragma unroll
  for (int nt = 0; nt < NT; ++nt) {
    int gcol = col0 + wn0 + nt * 16 + l16;
    float bc = (MODE == 2) ? 0.f : bias[gcol];
#pragma unroll
    for (int mt = 0; mt < 2; ++mt) {
#pragma unroll
      for (int r = 0; r < 4; ++r) {
        float v = acc[mt][nt][r];
        int rr = row0 + wm0 + mt * 16 + q * 4 + r;
        if (MODE == 0) {
          float tv = tanhf(bc + v);
          size_t o = (size_t)rr * N + gcol;
          split_store(tv, &Oh[o], &Ol[o]);
        } else if (MODE == 1) {
          int b = rr / D, u = rr - b * D;
          size_t ob = (size_t)(b * Dn) * N + gcol;
          size_t om = ob + (size_t)(1 + 2 * u) * N;
          size_t op = ob + (size_t)(2 + 2 * u) * N;
          split_store(tanhf(bc - v), &Oh[om], &Ol[om]);
          split_store(tanhf(bc + v), &Oh[op], &Ol[op]);
          if (u == 0) split_store(tanhf(bc), &Oh[ob], &Ol[ob]);
        } else {
          Of[(size_t)rr * N + gcol] = v;
        }
      }
    }
  }
}

// Row sum-of-squares of C5 classes from hi/lo (fixed order -> exact dup ties).
__global__ void __launch_bounds__(256)
rownorm_hl(const short* __restrict__ hi, const short* __restrict__ lo,
           float* __restrict__ ns) {
  int row = blockIdx.x;
  int t = threadIdx.x;
  size_t base = (size_t)row * 1024 + t * 4;
  short4 h = *(const short4*)&hi[base];
  short4 l = *(const short4*)&lo[base];
  float v0 = bf2f(h.x) + bf2f(l.x);
  float v1 = bf2f(h.y) + bf2f(l.y);
  float v2 = bf2f(h.z) + bf2f(l.z);
  float v3 = bf2f(h.w) + bf2f(l.w);
  float s = v0 * v0 + v1 * v1 + v2 * v2 + v3 * v3;
  __shared__ float red[256];
  red[t] = s;
  __syncthreads();
  for (int off = 128; off; off >>= 1) {
    if (t < off) red[t] += red[t + off];
    __syncthreads();
  }
  if (t == 0) ns[row] = red[0];
}

// Prune after layer 4: 243 entries e = 3*j + t4; class via base-3 digit fold.
__global__ void __launch_bounds__(256)
prune4_k(const float* __restrict__ ns, int* __restrict__ kept4) {
  int b = blockIdx.x, t = threadIdx.x;
  __shared__ float nss[31];
  __shared__ float key[243];
  __shared__ int cls[243];
  if (t < 31) nss[t] = ns[b * 31 + t];
  __syncthreads();
  if (t < 243) {
    int j = t / 3, t4 = t - 3 * j;
    int d0 = j / 27, d1 = (j / 9) % 3, d2 = (j / 3) % 3, d3 = j % 3;
    int u = 0;
    u = (d0 == 1) ? 0 : (1 + 2 * u + (d0 == 2));
    u = (d1 == 1) ? 0 : (1 + 2 * u + (d1 == 2));
    u = (d2 == 1) ? 0 : (1 + 2 * u + (d2 == 2));
    u = (d3 == 1) ? 0 : (1 + 2 * u + (d3 == 2));
    cls[t] = u;
    key[t] = (t4 == 1) ? 0.f : nss[u];
  }
  __syncthreads();
  if (t < 243) {
    float k = key[t];
    int rank = 0;
    for (int e = 0; e < 243; ++e) {
      float ke = key[e];
      rank += (ke > k) || (ke == k && e < t);
    }
    if (rank < 128) {
      int t4 = t - 3 * (t / 3);
      kept4[b * 128 + rank] = (cls[t] << 1) | (t4 == 2 ? 1 : 0);
    }
  }
}

// Per-class stats of Y5 rows: dot(b5,Y), ||Y||^2; block 3968 computes ||b5||^2.
__global__ void __launch_bounds__(256)
stats5_k(const float* __restrict__ Y5, const float* __restrict__ b5,
         float* __restrict__ dotv, float* __restrict__ nrmv,
         float* __restrict__ nb5) {
  int row = blockIdx.x;
  int t = threadIdx.x;
  __shared__ float rd[256], rn[256];
  if (row < 3968) {
    const float* y = Y5 + (size_t)row * 512;
    float d = 0.f, n2 = 0.f;
    for (int o = t; o < 512; o += 256) {
      float v = y[o];
      d = fmaf(b5[o], v, d);
      n2 = fmaf(v, v, n2);
    }
    rd[t] = d;
    rn[t] = n2;
    __syncthreads();
    for (int off = 128; off; off >>= 1) {
      if (t < off) {
        rd[t] += rd[t + off];
        rn[t] += rn[t + off];
      }
      __syncthreads();
    }
    if (t == 0) {
      dotv[row] = rd[0];
      nrmv[row] = rn[0];
    }
  } else {
    float n2 = 0.f;
    for (int o = t; o < 512; o += 256) {
      float v = b5[o];
      n2 = fmaf(v, v, n2);
    }
    rn[t] = n2;
    __syncthreads();
    for (int off = 128; off; off >>= 1) {
      if (t < off) rn[t] += rn[t + off];
      __syncthreads();
    }
    if (t == 0) nb5[0] = rn[0];
  }
}

// Final prune 384->128. Key per (class,sign) computed once -> exact ties.
__global__ void __launch_bounds__(384)
prune5_k(const float* __restrict__ dotv, const float* __restrict__ nrmv,
         const float* __restrict__ nb5, const int* __restrict__ kept4,
         int* __restrict__ kept5) {
  int b = blockIdx.x, t = threadIdx.x;
  __shared__ float pns[128];
  __shared__ float key[384];
  if (t < 128) {
    int k4 = kept4[b * 128 + t];
    int c = k4 >> 1;
    float s = (k4 & 1) ? 1.f : -1.f;
    pns[t] = nb5[0] + nrmv[b * 31 + c] + s * 2.f * dotv[b * 31 + c];
  }
  __syncthreads();
  int m = t / 3, tt = t - 3 * m;
  key[t] = (tt == 1) ? 0.f : pns[m];
  __syncthreads();
  float k = key[t];
  int rank = 0;
  for (int e = 0; e < 384; ++e) {
    float ke = key[e];
    rank += (ke > k) || (ke == k && e < t);
  }
  if (rank < 128) kept5[b * 128 + rank] = (m << 1) | (tt == 2 ? 1 : 0);
}

// Final data (B,512,128) + argmax-|.| output (B,512).
__global__ void __launch_bounds__(256)
finalize_k(const float* __restrict__ Y5, const float* __restrict__ b5,
           const int* __restrict__ kept4, const int* __restrict__ kept5,
           float* __restrict__ out, float* __restrict__ dataout) {
  const int b = blockIdx.y;
  const int o0 = blockIdx.x * 64;
  __shared__ float Ys[31][65];
  __shared__ float bias_s[64];
  __shared__ float vt[64][130];
  __shared__ float ra[64][4];
  __shared__ float rv[64][4];
  const int t = threadIdx.x;
  for (int idx = t; idx < 31 * 64; idx += 256) {
    int c = idx >> 6, o = idx & 63;
    Ys[c][o] = Y5[((size_t)b * 31 + c) * 512 + o0 + o];
  }
  if (t < 64) bias_s[t] = b5[o0 + t];
  const int rr = t & 127, oh = t >> 7;
  int k5 = kept5[b * 128 + rr];
  int m = k5 >> 1;
  float sig = (k5 & 1) ? 1.f : -1.f;
  int k4 = kept4[b * 128 + m];
  int cc = k4 >> 1;
  float s4 = (k4 & 1) ? 1.f : -1.f;
  float afac = sig * s4;
  __syncthreads();
#pragma unroll
  for (int ol = 0; ol < 32; ++ol) {
    int o = oh * 32 + ol;
    float v = sig * bias_s[o] + afac * Ys[cc][o];
    dataout[((size_t)b * 512 + o0 + o) * 128 + rr] = v;
    vt[o][rr] = v;
  }
  __syncthreads();
  int o = t >> 2, q = t & 3;
  float bestv = vt[o][q * 32];
  float besta = fabsf(bestv);
  for (int i = 1; i < 32; ++i) {
    float v = vt[o][q * 32 + i];
    float a = fabsf(v);
    if (a > besta) {
      besta = a;
      bestv = v;
    }
  }
  ra[o][q] = besta;
  rv[o][q] = bestv;
  __syncthreads();
  if (t < 64) {
    float ba = ra[t][0], bv = rv[t][0];
#pragma unroll
    for (int qq = 1; qq < 4; ++qq) {
      if (ra[t][qq] > ba) {
        ba = ra[t][qq];
        bv = rv[t][qq];
      }
    }
    out[(size_t)b * 512 + o0 + t] = bv;
  }
}

extern "C" void kernel_launch(void* const* d_in, const int* in_sizes, int n_in,
                              void* d_out, int out_size, void* d_ws,
                              size_t ws_size, hipStream_t stream) {
  const float* x = (const float*)d_in[0];
  const float* Wt[6];
  const float* bs[6];
  for (int i = 0; i < 6; ++i) {
    Wt[i] = (const float*)d_in[1 + 2 * i];
    bs[i] = (const float*)d_in[2 + 2 * i];
  }
  char* base = (char*)d_ws;
  // Byte-offset layout (37.4 MB total; aliases are strictly lifetime-disjoint
  // in stream order: C5 over dead W0-W3, Y5 over dead C1-C4).
  short* A0h = (short*)(base + 0);
  short* A0l = (short*)(base + 262144);
  short* Wh[6], *Wl[6];
  {
    size_t off = 524288;
    for (int i = 0; i < 6; ++i) {
      size_t sz = (i < 5) ? 2097152 : 1048576;  // bytes per array
      Wh[i] = (short*)(base + off);
      Wl[i] = (short*)(base + off + sz);
      off += 2 * sz;
    }
  }
  short* C1h = (short*)(base + 23592960), *C1l = (short*)(base + 23855104);
  short* C2h = (short*)(base + 24117248), *C2l = (short*)(base + 24903680);
  short* C3h = (short*)(base + 25690112), *C3l = (short*)(base + 27525120);
  short* C4h = (short*)(base + 29360128), *C4l = (short*)(base + 33292288);
  short* C5h = (short*)(base + 524288);    // over W0h..W1l (dead after L1)
  short* C5l = (short*)(base + 8912896);   // over W2h..W3l (dead after L3)
  float* Y5 = (float*)(base + 23592960);   // over C1..C4 (dead after L4)
  float* ns = (float*)(base + 37224448);
  float* dotv = (float*)(base + 37240320);
  float* nrmv = (float*)(base + 37256192);
  float* nb5 = (float*)(base + 37272064);
  int* kept4 = (int*)(base + 37272068);
  int* kept5 = (int*)(base + 37337604);
  float* outp = (float*)d_out;
  float* dataout = outp + 128 * 512;

  dim3 blk(256);
  packx_k<<<dim3(128), blk, 0, stream>>>(x, A0h, A0l);
  for (int i = 0; i < 5; ++i)
    transW_k<<<dim3(16, 16), blk, 0, stream>>>(Wt[i], Wh[i], Wl[i], 1024);
  transW_k<<<dim3(8, 16), blk, 0, stream>>>(Wt[5], Wh[5], Wl[5], 512);

  // L0: x -> C1 (128 rows)
  mfma_gemm<64, 0, 1><<<dim3(16, 2), blk, 0, stream>>>(
      A0h, A0l, Wh[0], Wl[0], bs[0], C1h, C1l, nullptr, 1024, 1);
  // L1: C1 (128) -> C2 (384)
  mfma_gemm<64, 1, 1><<<dim3(16, 2), blk, 0, stream>>>(
      C1h, C1l, Wh[1], Wl[1], bs[1], C2h, C2l, nullptr, 1024, 3);
  // L2: C2 (384) -> C3 (896)
  mfma_gemm<64, 1, 3><<<dim3(16, 6), blk, 0, stream>>>(
      C2h, C2l, Wh[2], Wl[2], bs[2], C3h, C3l, nullptr, 1024, 7);
  // L3: C3 (896) -> C4 (1920)
  mfma_gemm<128, 1, 7><<<dim3(8, 14), blk, 0, stream>>>(
      C3h, C3l, Wh[3], Wl[3], bs[3], C4h, C4l, nullptr, 1024, 15);
  // L4: C4 (1920) -> C5 (3968)
  mfma_gemm<128, 1, 15><<<dim3(8, 30), blk, 0, stream>>>(
      C4h, C4l, Wh[4], Wl[4], bs[4], C5h, C5l, nullptr, 1024, 31);
  // Prune 243 -> 128
  rownorm_hl<<<dim3(3968), blk, 0, stream>>>(C5h, C5l, ns);
  prune4_k<<<dim3(128), blk, 0, stream>>>(ns, kept4);
  // L5: C5 (3968) -> Y5 raw fp32 (3968 x 512)
  mfma_gemm<128, 2, 31><<<dim3(4, 62), blk, 0, stream>>>(
      C5h, C5l, Wh[5], Wl[5], nullptr, nullptr, nullptr, Y5, 512, 0);
  // Final prune + output
  stats5_k<<<dim3(3969), blk, 0, stream>>>(Y5, bs[5], dotv, nrmv, nb5);
  prune5_k<<<dim3(128), dim3(384), 0, stream>>>(dotv, nrmv, nb5, kept4, kept5);
  finalize_k<<<dim3(8, 128), blk, 0, stream>>>(Y5, bs[5], kept4, kept5, outp,
                                               dataout);
}

// Round 4
// 238.522 us; speedup vs baseline: 1.7102x; 1.7102x over previous
//
#include <hip/hip_runtime.h>
#include <math.h>

// PathPreservingNetwork — factored-class + bf16x3 MFMA, R4.
// Classes per layer input: 1,1,3,7,15,31; every path value is s*C[class].
// R4: BN=64 tiles (2x more blocks), __launch_bounds__(256,2) for 2 blocks/CU,
// register-prefetch software pipeline, split-K for L0-L3 (starved grids),
// single merged transpose kernel.

using s8v = __attribute__((ext_vector_type(8))) short;
using f4v = __attribute__((ext_vector_type(4))) float;

__device__ __forceinline__ float bf2f(short b) {
  unsigned u = ((unsigned)(unsigned short)b) << 16;
  return __builtin_bit_cast(float, u);
}
__device__ __forceinline__ short f2bf(float f) {
  unsigned u = __builtin_bit_cast(unsigned, f);
  u = (u + 0x7FFFu + ((u >> 16) & 1u)) >> 16;
  return (short)u;
}
__device__ __forceinline__ void split_store(float f, short* hi, short* lo) {
  short h = f2bf(f);
  *hi = h;
  *lo = f2bf(f - bf2f(h));
}

// Pack fp32 x (128x1024) into hi/lo bf16 arrays.
__global__ void __launch_bounds__(256)
packx_k(const float* __restrict__ x, short* __restrict__ hi,
        short* __restrict__ lo) {
  int i = (blockIdx.x * 256 + threadIdx.x) * 4;
  float4 v = *(const float4*)&x[i];
  short4 h, l;
  h.x = f2bf(v.x); l.x = f2bf(v.x - bf2f(h.x));
  h.y = f2bf(v.y); l.y = f2bf(v.y - bf2f(h.y));
  h.z = f2bf(v.z); l.z = f2bf(v.z - bf2f(h.z));
  h.w = f2bf(v.w); l.w = f2bf(v.w - bf2f(h.w));
  *(short4*)&hi[i] = h;
  *(short4*)&lo[i] = l;
}

// Transpose+split all six W (1024 x N fp32) -> (N x 1024 bf16 hi/lo), one launch.
struct TWArgs {
  const float* W[6];
  short* Th[6];
  short* Tl[6];
};
__global__ void __launch_bounds__(256)
transW_all(TWArgs a) {
  const int z = blockIdx.z;
  const int N = (z == 5) ? 512 : 1024;
  const int n0 = blockIdx.x * 64, k0 = blockIdx.y * 64;
  if (n0 >= N) return;
  const float* __restrict__ W = a.W[z];
  short* __restrict__ Th = a.Th[z];
  short* __restrict__ Tl = a.Tl[z];
  __shared__ float tile[64][65];
  const int t = threadIdx.x;
  const int r = t >> 4, c4 = (t & 15) * 4;
#pragma unroll
  for (int i = 0; i < 4; ++i) {
    int rr = r + 16 * i;
    float4 v = *(const float4*)&W[(size_t)(k0 + rr) * N + n0 + c4];
    tile[rr][c4 + 0] = v.x;
    tile[rr][c4 + 1] = v.y;
    tile[rr][c4 + 2] = v.z;
    tile[rr][c4 + 3] = v.w;
  }
  __syncthreads();
#pragma unroll
  for (int i = 0; i < 4; ++i) {
    int n = r + 16 * i;
    short4 h, l;
    float f0 = tile[c4 + 0][n], f1 = tile[c4 + 1][n];
    float f2 = tile[c4 + 2][n], f3 = tile[c4 + 3][n];
    h.x = f2bf(f0); l.x = f2bf(f0 - bf2f(h.x));
    h.y = f2bf(f1); l.y = f2bf(f1 - bf2f(h.y));
    h.z = f2bf(f2); l.z = f2bf(f2 - bf2f(h.z));
    h.w = f2bf(f3); l.w = f2bf(f3 - bf2f(h.w));
    size_t o = (size_t)(n0 + n) * 1024 + k0 + c4;
    *(short4*)&Th[o] = h;
    *(short4*)&Tl[o] = l;
  }
}

// ------------------------------------------------------------- MFMA GEMM ----
// A (M x 1024) hi/lo bf16 row-major; Wt (N x 1024) hi/lo bf16 row-major.
// Block tile 64x64, 4 waves 2x2, wave tile 32x32 (2x2 16-tiles, 12 MFMA/iter).
// Register-prefetch pipeline: next K-slab loads issue between LDS-write and
// MFMA phase. BKP=40 pad -> <=2-way LDS conflicts (free, m136).
// MODE 1: fused epilogue rows b*Dn+1+2u / +2+2u = tanh(bias -/+ acc), plus
//         zero row tanh(bias) at u==0. (hi/lo bf16 out)
// MODE 2: Of[rr*N+col] = acc (raw fp32)
// MODE 3: split-K partial: Of[(bz*R + rr)*N + col] = acc
template <int MODE, int D, int KS>
__global__ void __launch_bounds__(256, 2)
mfma_gemm(const short* __restrict__ Ah, const short* __restrict__ Al,
          const short* __restrict__ Bh, const short* __restrict__ Bl,
          const float* __restrict__ bias, short* __restrict__ Oh,
          short* __restrict__ Ol, float* __restrict__ Of, int N, int Dn) {
  constexpr int KC = 1024 / KS;
  constexpr int BKP = 40;
  __shared__ short As_h[64 * BKP], As_l[64 * BKP];
  __shared__ short Bs_h[64 * BKP], Bs_l[64 * BKP];
  const int t = threadIdx.x;
  const int row0 = blockIdx.y * 64;
  const int col0 = blockIdx.x * 64;
  const int kb = blockIdx.z * KC;
  const int sr = t >> 2, sko = (t & 3) * 8;
  const short* Ahp = Ah + (size_t)(row0 + sr) * 1024 + kb + sko;
  const short* Alp = Al + (size_t)(row0 + sr) * 1024 + kb + sko;
  const short* Bhp = Bh + (size_t)(col0 + sr) * 1024 + kb + sko;
  const short* Blp = Bl + (size_t)(col0 + sr) * 1024 + kb + sko;
  const int w = t >> 6, lane = t & 63;
  const int l16 = lane & 15, q = lane >> 4;
  const int wm0 = (w & 1) * 32, wn0 = (w >> 1) * 32;
  const int abase = (wm0 + l16) * BKP + q * 8;
  const int bbase = (wn0 + l16) * BKP + q * 8;
  f4v acc[2][2];
#pragma unroll
  for (int i = 0; i < 2; ++i)
#pragma unroll
    for (int j = 0; j < 2; ++j) acc[i][j] = (f4v){0.f, 0.f, 0.f, 0.f};
  uint4 rah = *(const uint4*)(Ahp);
  uint4 ral = *(const uint4*)(Alp);
  uint4 rbh = *(const uint4*)(Bhp);
  uint4 rbl = *(const uint4*)(Blp);
  for (int k0 = 0; k0 < KC; k0 += 32) {
    __syncthreads();
    *(uint4*)&As_h[sr * BKP + sko] = rah;
    *(uint4*)&As_l[sr * BKP + sko] = ral;
    *(uint4*)&Bs_h[sr * BKP + sko] = rbh;
    *(uint4*)&Bs_l[sr * BKP + sko] = rbl;
    if (k0 + 32 < KC) {  // prefetch next slab; waits land before next LDS-write
      rah = *(const uint4*)(Ahp + k0 + 32);
      ral = *(const uint4*)(Alp + k0 + 32);
      rbh = *(const uint4*)(Bhp + k0 + 32);
      rbl = *(const uint4*)(Blp + k0 + 32);
    }
    __syncthreads();
    s8v ah[2], al[2], bh[2], bl[2];
#pragma unroll
    for (int mt = 0; mt < 2; ++mt) {
      ah[mt] = *(const s8v*)&As_h[abase + mt * 16 * BKP];
      al[mt] = *(const s8v*)&As_l[abase + mt * 16 * BKP];
    }
#pragma unroll
    for (int nt = 0; nt < 2; ++nt) {
      bh[nt] = *(const s8v*)&Bs_h[bbase + nt * 16 * BKP];
      bl[nt] = *(const s8v*)&Bs_l[bbase + nt * 16 * BKP];
    }
#pragma unroll
    for (int mt = 0; mt < 2; ++mt)
#pragma unroll
      for (int nt = 0; nt < 2; ++nt) {
        acc[mt][nt] = __builtin_amdgcn_mfma_f32_16x16x32_bf16(
            ah[mt], bh[nt], acc[mt][nt], 0, 0, 0);
        acc[mt][nt] = __builtin_amdgcn_mfma_f32_16x16x32_bf16(
            ah[mt], bl[nt], acc[mt][nt], 0, 0, 0);
        acc[mt][nt] = __builtin_amdgcn_mfma_f32_16x16x32_bf16(
            al[mt], bh[nt], acc[mt][nt], 0, 0, 0);
      }
  }
  const int R = (int)gridDim.y << 6;
#pragma unroll
  for (int nt = 0; nt < 2; ++nt) {
    int gcol = col0 + wn0 + nt * 16 + l16;
    float bc = (MODE == 1) ? bias[gcol] : 0.f;
#pragma unroll
    for (int mt = 0; mt < 2; ++mt) {
#pragma unroll
      for (int r = 0; r < 4; ++r) {
        float v = acc[mt][nt][r];
        int rr = row0 + wm0 + mt * 16 + q * 4 + r;
        if (MODE == 1) {
          int b = rr / D, u = rr - b * D;
          size_t ob = (size_t)(b * Dn) * N + gcol;
          size_t om = ob + (size_t)(1 + 2 * u) * N;
          size_t op = ob + (size_t)(2 + 2 * u) * N;
          split_store(tanhf(bc - v), &Oh[om], &Ol[om]);
          split_store(tanhf(bc + v), &Oh[op], &Ol[op]);
          if (u == 0) split_store(tanhf(bc), &Oh[ob], &Ol[ob]);
        } else if (MODE == 2) {
          Of[(size_t)rr * N + gcol] = v;
        } else {
          Of[((size_t)blockIdx.z * R + rr) * N + gcol] = v;
        }
      }
    }
  }
}

// Combine split-K partials, layer 0: out = tanh(bias + sum) -> hi/lo.
template <int KS>
__global__ void __launch_bounds__(256)
comb0_hl(const float* __restrict__ P, const float* __restrict__ bias,
         short* __restrict__ Oh, short* __restrict__ Ol, int R, int N) {
  int i = blockIdx.x * 256 + threadIdx.x;
  int n4 = N >> 2;
  int r = i / n4, c4 = (i - r * n4) * 4;
  float4 y = *(const float4*)&P[(size_t)r * N + c4];
  size_t stride = (size_t)R * N;
#pragma unroll
  for (int ks = 1; ks < KS; ++ks) {
    const float4 p = *(const float4*)&P[ks * stride + (size_t)r * N + c4];
    y.x += p.x; y.y += p.y; y.z += p.z; y.w += p.w;
  }
  float4 bc = *(const float4*)(bias + c4);
  float t0 = tanhf(bc.x + y.x), t1 = tanhf(bc.y + y.y);
  float t2 = tanhf(bc.z + y.z), t3 = tanhf(bc.w + y.w);
  short4 h, l;
  h.x = f2bf(t0); l.x = f2bf(t0 - bf2f(h.x));
  h.y = f2bf(t1); l.y = f2bf(t1 - bf2f(h.y));
  h.z = f2bf(t2); l.z = f2bf(t2 - bf2f(h.z));
  h.w = f2bf(t3); l.w = f2bf(t3 - bf2f(h.w));
  *(short4*)&Oh[(size_t)r * N + c4] = h;
  *(short4*)&Ol[(size_t)r * N + c4] = l;
}

// Combine split-K partials, layers 1..3: rows b*Dn+1+2u (tanh(b-y)) and
// b*Dn+2+2u (tanh(b+y)); zero row tanh(b) at u==0. hi/lo out.
template <int KS, int D>
__global__ void __launch_bounds__(256)
comb1_hl(const float* __restrict__ P, const float* __restrict__ bias,
         short* __restrict__ Oh, short* __restrict__ Ol, int R, int N,
         int Dn) {
  int i = blockIdx.x * 256 + threadIdx.x;
  int n4 = N >> 2;
  int r = i / n4, c4 = (i - r * n4) * 4;
  int b = r / D, u = r - b * D;
  float4 y = *(const float4*)&P[(size_t)r * N + c4];
  size_t stride = (size_t)R * N;
#pragma unroll
  for (int ks = 1; ks < KS; ++ks) {
    const float4 p = *(const float4*)&P[ks * stride + (size_t)r * N + c4];
    y.x += p.x; y.y += p.y; y.z += p.z; y.w += p.w;
  }
  float4 bc = *(const float4*)(bias + c4);
  size_t ob = (size_t)(b * Dn) * N + c4;
  size_t om = ob + (size_t)(1 + 2 * u) * N;
  size_t op = ob + (size_t)(2 + 2 * u) * N;
  {
    float t0 = tanhf(bc.x - y.x), t1 = tanhf(bc.y - y.y);
    float t2 = tanhf(bc.z - y.z), t3 = tanhf(bc.w - y.w);
    short4 h, l;
    h.x = f2bf(t0); l.x = f2bf(t0 - bf2f(h.x));
    h.y = f2bf(t1); l.y = f2bf(t1 - bf2f(h.y));
    h.z = f2bf(t2); l.z = f2bf(t2 - bf2f(h.z));
    h.w = f2bf(t3); l.w = f2bf(t3 - bf2f(h.w));
    *(short4*)&Oh[om] = h;
    *(short4*)&Ol[om] = l;
  }
  {
    float t0 = tanhf(bc.x + y.x), t1 = tanhf(bc.y + y.y);
    float t2 = tanhf(bc.z + y.z), t3 = tanhf(bc.w + y.w);
    short4 h, l;
    h.x = f2bf(t0); l.x = f2bf(t0 - bf2f(h.x));
    h.y = f2bf(t1); l.y = f2bf(t1 - bf2f(h.y));
    h.z = f2bf(t2); l.z = f2bf(t2 - bf2f(h.z));
    h.w = f2bf(t3); l.w = f2bf(t3 - bf2f(h.w));
    *(short4*)&Oh[op] = h;
    *(short4*)&Ol[op] = l;
  }
  if (u == 0) {
    float t0 = tanhf(bc.x), t1 = tanhf(bc.y);
    float t2 = tanhf(bc.z), t3 = tanhf(bc.w);
    short4 h, l;
    h.x = f2bf(t0); l.x = f2bf(t0 - bf2f(h.x));
    h.y = f2bf(t1); l.y = f2bf(t1 - bf2f(h.y));
    h.z = f2bf(t2); l.z = f2bf(t2 - bf2f(h.z));
    h.w = f2bf(t3); l.w = f2bf(t3 - bf2f(h.w));
    *(short4*)&Oh[ob] = h;
    *(short4*)&Ol[ob] = l;
  }
}

// Row sum-of-squares of C5 classes from hi/lo (fixed order -> exact dup ties).
__global__ void __launch_bounds__(256)
rownorm_hl(const short* __restrict__ hi, const short* __restrict__ lo,
           float* __restrict__ ns) {
  int row = blockIdx.x;
  int t = threadIdx.x;
  size_t base = (size_t)row * 1024 + t * 4;
  short4 h = *(const short4*)&hi[base];
  short4 l = *(const short4*)&lo[base];
  float v0 = bf2f(h.x) + bf2f(l.x);
  float v1 = bf2f(h.y) + bf2f(l.y);
  float v2 = bf2f(h.z) + bf2f(l.z);
  float v3 = bf2f(h.w) + bf2f(l.w);
  float s = v0 * v0 + v1 * v1 + v2 * v2 + v3 * v3;
  __shared__ float red[256];
  red[t] = s;
  __syncthreads();
  for (int off = 128; off; off >>= 1) {
    if (t < off) red[t] += red[t + off];
    __syncthreads();
  }
  if (t == 0) ns[row] = red[0];
}

// Prune after layer 4: 243 entries e = 3*j + t4; class via base-3 digit fold.
__global__ void __launch_bounds__(256)
prune4_k(const float* __restrict__ ns, int* __restrict__ kept4) {
  int b = blockIdx.x, t = threadIdx.x;
  __shared__ float nss[31];
  __shared__ float key[243];
  __shared__ int cls[243];
  if (t < 31) nss[t] = ns[b * 31 + t];
  __syncthreads();
  if (t < 243) {
    int j = t / 3, t4 = t - 3 * j;
    int d0 = j / 27, d1 = (j / 9) % 3, d2 = (j / 3) % 3, d3 = j % 3;
    int u = 0;
    u = (d0 == 1) ? 0 : (1 + 2 * u + (d0 == 2));
    u = (d1 == 1) ? 0 : (1 + 2 * u + (d1 == 2));
    u = (d2 == 1) ? 0 : (1 + 2 * u + (d2 == 2));
    u = (d3 == 1) ? 0 : (1 + 2 * u + (d3 == 2));
    cls[t] = u;
    key[t] = (t4 == 1) ? 0.f : nss[u];
  }
  __syncthreads();
  if (t < 243) {
    float k = key[t];
    int rank = 0;
    for (int e = 0; e < 243; ++e) {
      float ke = key[e];
      rank += (ke > k) || (ke == k && e < t);
    }
    if (rank < 128) {
      int t4 = t - 3 * (t / 3);
      kept4[b * 128 + rank] = (cls[t] << 1) | (t4 == 2 ? 1 : 0);
    }
  }
}

// Per-class stats of Y5 rows: dot(b5,Y), ||Y||^2; block 3968 computes ||b5||^2.
__global__ void __launch_bounds__(256)
stats5_k(const float* __restrict__ Y5, const float* __restrict__ b5,
         float* __restrict__ dotv, float* __restrict__ nrmv,
         float* __restrict__ nb5) {
  int row = blockIdx.x;
  int t = threadIdx.x;
  __shared__ float rd[256], rn[256];
  if (row < 3968) {
    const float* y = Y5 + (size_t)row * 512;
    float d = 0.f, n2 = 0.f;
    for (int o = t; o < 512; o += 256) {
      float v = y[o];
      d = fmaf(b5[o], v, d);
      n2 = fmaf(v, v, n2);
    }
    rd[t] = d;
    rn[t] = n2;
    __syncthreads();
    for (int off = 128; off; off >>= 1) {
      if (t < off) {
        rd[t] += rd[t + off];
        rn[t] += rn[t + off];
      }
      __syncthreads();
    }
    if (t == 0) {
      dotv[row] = rd[0];
      nrmv[row] = rn[0];
    }
  } else {
    float n2 = 0.f;
    for (int o = t; o < 512; o += 256) {
      float v = b5[o];
      n2 = fmaf(v, v, n2);
    }
    rn[t] = n2;
    __syncthreads();
    for (int off = 128; off; off >>= 1) {
      if (t < off) rn[t] += rn[t + off];
      __syncthreads();
    }
    if (t == 0) nb5[0] = rn[0];
  }
}

// Final prune 384->128. Key per (class,sign) computed once -> exact ties.
__global__ void __launch_bounds__(384)
prune5_k(const float* __restrict__ dotv, const float* __restrict__ nrmv,
         const float* __restrict__ nb5, const int* __restrict__ kept4,
         int* __restrict__ kept5) {
  int b = blockIdx.x, t = threadIdx.x;
  __shared__ float pns[128];
  __shared__ float key[384];
  if (t < 128) {
    int k4 = kept4[b * 128 + t];
    int c = k4 >> 1;
    float s = (k4 & 1) ? 1.f : -1.f;
    pns[t] = nb5[0] + nrmv[b * 31 + c] + s * 2.f * dotv[b * 31 + c];
  }
  __syncthreads();
  int m = t / 3, tt = t - 3 * m;
  key[t] = (tt == 1) ? 0.f : pns[m];
  __syncthreads();
  float k = key[t];
  int rank = 0;
  for (int e = 0; e < 384; ++e) {
    float ke = key[e];
    rank += (ke > k) || (ke == k && e < t);
  }
  if (rank < 128) kept5[b * 128 + rank] = (m << 1) | (tt == 2 ? 1 : 0);
}

// Final data (B,512,128) + argmax-|.| output (B,512).
__global__ void __launch_bounds__(256)
finalize_k(const float* __restrict__ Y5, const float* __restrict__ b5,
           const int* __restrict__ kept4, const int* __restrict__ kept5,
           float* __restrict__ out, float* __restrict__ dataout) {
  const int b = blockIdx.y;
  const int o0 = blockIdx.x * 64;
  __shared__ float Ys[31][65];
  __shared__ float bias_s[64];
  __shared__ float vt[64][130];
  __shared__ float ra[64][4];
  __shared__ float rv[64][4];
  const int t = threadIdx.x;
  for (int idx = t; idx < 31 * 64; idx += 256) {
    int c = idx >> 6, o = idx & 63;
    Ys[c][o] = Y5[((size_t)b * 31 + c) * 512 + o0 + o];
  }
  if (t < 64) bias_s[t] = b5[o0 + t];
  const int rr = t & 127, oh = t >> 7;
  int k5 = kept5[b * 128 + rr];
  int m = k5 >> 1;
  float sig = (k5 & 1) ? 1.f : -1.f;
  int k4 = kept4[b * 128 + m];
  int cc = k4 >> 1;
  float s4 = (k4 & 1) ? 1.f : -1.f;
  float afac = sig * s4;
  __syncthreads();
#pragma unroll
  for (int ol = 0; ol < 32; ++ol) {
    int o = oh * 32 + ol;
    float v = sig * bias_s[o] + afac * Ys[cc][o];
    dataout[((size_t)b * 512 + o0 + o) * 128 + rr] = v;
    vt[o][rr] = v;
  }
  __syncthreads();
  int o = t >> 2, q = t & 3;
  float bestv = vt[o][q * 32];
  float besta = fabsf(bestv);
  for (int i = 1; i < 32; ++i) {
    float v = vt[o][q * 32 + i];
    float a = fabsf(v);
    if (a > besta) {
      besta = a;
      bestv = v;
    }
  }
  ra[o][q] = besta;
  rv[o][q] = bestv;
  __syncthreads();
  if (t < 64) {
    float ba = ra[t][0], bv = rv[t][0];
#pragma unroll
    for (int qq = 1; qq < 4; ++qq) {
      if (ra[t][qq] > ba) {
        ba = ra[t][qq];
        bv = rv[t][qq];
      }
    }
    out[(size_t)b * 512 + o0 + t] = bv;
  }
}

extern "C" void kernel_launch(void* const* d_in, const int* in_sizes, int n_in,
                              void* d_out, int out_size, void* d_ws,
                              size_t ws_size, hipStream_t stream) {
  const float* x = (const float*)d_in[0];
  const float* Wt[6];
  const float* bs[6];
  for (int i = 0; i < 6; ++i) {
    Wt[i] = (const float*)d_in[1 + 2 * i];
    bs[i] = (const float*)d_in[2 + 2 * i];
  }
  char* base = (char*)d_ws;
  // Byte-offset layout, 37.4 MB (same proven footprint as R3). Aliases are
  // lifetime-disjoint in stream order:
  //   PA (split-K partials L0-L2) over C4h/C4l (written first at L3-comb)
  //   PB (split-K partials L3)    over W0/W1   (dead after L1)
  //   C5h over W0..W1, C5l over W2..W3 (dead after L3)
  //   Y5 over C1..C4 (dead after L4)
  short* A0h = (short*)(base + 0);
  short* A0l = (short*)(base + 262144);
  short* Wh[6], *Wl[6];
  {
    size_t off = 524288;
    for (int i = 0; i < 6; ++i) {
      size_t sz = (i < 5) ? 2097152 : 1048576;
      Wh[i] = (short*)(base + off);
      Wl[i] = (short*)(base + off + sz);
      off += 2 * sz;
    }
  }
  short* C1h = (short*)(base + 23592960), *C1l = (short*)(base + 23855104);
  short* C2h = (short*)(base + 24117248), *C2l = (short*)(base + 24903680);
  short* C3h = (short*)(base + 25690112), *C3l = (short*)(base + 27525120);
  short* C4h = (short*)(base + 29360128), *C4l = (short*)(base + 33292288);
  short* C5h = (short*)(base + 524288);
  short* C5l = (short*)(base + 8912896);
  float* PA = (float*)(base + 29360128);  // <=6.3 MB (L2 KS=4)
  float* PB = (float*)(base + 524288);    // 7.34 MB (L3 KS=2)
  float* Y5 = (float*)(base + 23592960);
  float* ns = (float*)(base + 37224448);
  float* dotv = (float*)(base + 37240320);
  float* nrmv = (float*)(base + 37256192);
  float* nb5 = (float*)(base + 37272064);
  int* kept4 = (int*)(base + 37272068);
  int* kept5 = (int*)(base + 37337604);
  float* outp = (float*)d_out;
  float* dataout = outp + 128 * 512;

  dim3 blk(256);
  packx_k<<<dim3(128), blk, 0, stream>>>(x, A0h, A0l);
  TWArgs twa;
  for (int i = 0; i < 6; ++i) {
    twa.W[i] = Wt[i];
    twa.Th[i] = Wh[i];
    twa.Tl[i] = Wl[i];
  }
  transW_all<<<dim3(16, 16, 6), blk, 0, stream>>>(twa);

  // L0: x -> C1 (split-K 4)
  mfma_gemm<3, 1, 4><<<dim3(16, 2, 4), blk, 0, stream>>>(
      A0h, A0l, Wh[0], Wl[0], nullptr, nullptr, nullptr, PA, 1024, 0);
  comb0_hl<4><<<dim3(128), blk, 0, stream>>>(PA, bs[0], C1h, C1l, 128, 1024);
  // L1: C1 -> C2 (split-K 4)
  mfma_gemm<3, 1, 4><<<dim3(16, 2, 4), blk, 0, stream>>>(
      C1h, C1l, Wh[1], Wl[1], nullptr, nullptr, nullptr, PA, 1024, 0);
  comb1_hl<4, 1><<<dim3(128), blk, 0, stream>>>(PA, bs[1], C2h, C2l, 128, 1024,
                                                3);
  // L2: C2 (384) -> C3 (split-K 4)
  mfma_gemm<3, 3, 4><<<dim3(16, 6, 4), blk, 0, stream>>>(
      C2h, C2l, Wh[2], Wl[2], nullptr, nullptr, nullptr, PA, 1024, 0);
  comb1_hl<4, 3><<<dim3(384), blk, 0, stream>>>(PA, bs[2], C3h, C3l, 384, 1024,
                                                7);
  // L3: C3 (896) -> C4 (split-K 2, partials over dead W0/W1)
  mfma_gemm<3, 7, 2><<<dim3(16, 14, 2), blk, 0, stream>>>(
      C3h, C3l, Wh[3], Wl[3], nullptr, nullptr, nullptr, PB, 1024, 0);
  comb1_hl<2, 7><<<dim3(896), blk, 0, stream>>>(PB, bs[3], C4h, C4l, 896, 1024,
                                                15);
  // L4: C4 (1920) -> C5 (3968), fused epilogue
  mfma_gemm<1, 15, 1><<<dim3(16, 30), blk, 0, stream>>>(
      C4h, C4l, Wh[4], Wl[4], bs[4], C5h, C5l, nullptr, 1024, 31);
  // Prune 243 -> 128
  rownorm_hl<<<dim3(3968), blk, 0, stream>>>(C5h, C5l, ns);
  prune4_k<<<dim3(128), blk, 0, stream>>>(ns, kept4);
  // L5: C5 -> Y5 raw fp32 (3968 x 512)
  mfma_gemm<2, 31, 1><<<dim3(8, 62), blk, 0, stream>>>(
      C5h, C5l, Wh[5], Wl[5], nullptr, nullptr, nullptr, Y5, 512, 0);
  // Final prune + output
  stats5_k<<<dim3(3969), blk, 0, stream>>>(Y5, bs[5], dotv, nrmv, nb5);
  prune5_k<<<dim3(128), dim3(384), 0, stream>>>(dotv, nrmv, nb5, kept4, kept5);
  finalize_k<<<dim3(8, 128), blk, 0, stream>>>(Y5, bs[5], kept4, kept5, outp,
                                               dataout);
}